// Round 15
// baseline (2651.539 us; speedup 1.0000x reference)
//
#include <hip/hip_runtime.h>
#include <stdint.h>
#include <stddef.h>

// RNNPredictorBurnin — round 15: r14 + 2-phase double-buffered LDS in the
// step kernel (T3-minimum recipe): stage(kt+1)->buf^1, compute buf, ONE
// __syncthreads per kt (its vmcnt(0) is the "next tile ready" wait).
// Math identical to r11/r14: f16 2-plane scaled split, 3 terms (~2^-22),
// folded W_comb, gate-interleaved Wbig, fused GRU epilogue, fp32 master h.

typedef _Float16 f16x8 __attribute__((ext_vector_type(8)));
typedef float f32x4  __attribute__((ext_vector_type(4)));

__device__ __forceinline__ void split2h(float v, _Float16& a, _Float16& b) {
    a = (_Float16)v;
    b = (_Float16)((v - (float)a) * 2048.0f);
}

__device__ __forceinline__ int swz(int row, int col) {   // LDS byte address
    return row * 128 + (col ^ ((row & 7) << 4));
}

__device__ __forceinline__ void gload16(const char* src, char* ldsdst) {
    __builtin_amdgcn_global_load_lds(
        (const __attribute__((address_space(1))) void*)src,
        (__attribute__((address_space(3))) void*)ldsdst, 16, 0, 0);
}

// ===========================================================================
// Step kernel: 64x64 tile, 4 waves, 2 x 32KB LDS buffers (per buffer:
// A0@0 A1@8K B0@16K B1@24K). Staging: 8 global_load_lds per wave per kt,
// linear LDS dest + inverse-swizzled per-lane source (rule #21, r4==r5
// bit-identity verified); reads use swz(). 2-phase pipeline:
//   prologue stage(0); sync;  loop: stage(kt+1)->other buf, MFMA(buf), sync.
// Grid: steps 640 = 8 XCD x (8 mt x 10 nt); final 128 = 8 mt x 16 out-nt.
// ===========================================================================
__global__ __launch_bounds__(256) void gemm_step64(
    const _Float16* __restrict__ hc0, const _Float16* __restrict__ hc1,
    const _Float16* __restrict__ W0,  const _Float16* __restrict__ W1,
    _Float16* __restrict__ hn0, _Float16* __restrict__ hn1,
    float* __restrict__ h32,
    float* __restrict__ outp,
    const float* __restrict__ bias_big,
    const float* __restrict__ W_ih,
    const float* __restrict__ act,
    int is_final)
{
    __shared__ alignas(16) char lds[65536];
    const int bid = blockIdx.x;
    int mt, nt;
    if (is_final) { mt = bid & 7; nt = 64 + (bid >> 3); }       // 128 blocks
    else { const int xcd = bid & 7, loc = bid >> 3;             // 640 blocks
           mt = loc & 7; nt = xcd * 10 + (loc >> 3); }          // nt 0..79
    const int nrow0 = (nt < 64) ? nt * 64 : 4096 + (nt - 64) * 64;

    const int tid  = threadIdx.x;
    const int wid  = tid >> 6;
    const int lane = tid & 63;
    const int wr = wid >> 1, wc = wid & 1;
    const int l16 = lane & 15, lq = lane >> 4;
    const int srcsw = (((lane & 7) ^ ((lane >> 3) & 7)) << 4);
    const int lrow = lane >> 3;

    // Per-lane global byte offsets (row part), constant across kt:
    const size_t aoff0 = (size_t)(mt * 64 + wid * 16 + lrow) * 2048 + srcsw;
    const size_t aoff1 = aoff0 + 8 * 2048;
    const size_t boff0 = (size_t)(nrow0 + wid * 16 + lrow) * 2048 + srcsw;
    const size_t boff1 = boff0 + 8 * 2048;
    const int dst0 = (wid * 16) * 128;          // wave-uniform LDS bases
    const int dst1 = (wid * 16 + 8) * 128;

    f32x4 acc0[2][2] = {}, accL[2][2] = {};

    auto stage = [&](int kt, char* buf) {
        const int ko = kt * 128;
        gload16((const char*)hc0 + aoff0 + ko, buf + dst0);
        gload16((const char*)hc0 + aoff1 + ko, buf + dst1);
        gload16((const char*)hc1 + aoff0 + ko, buf + 8192 + dst0);
        gload16((const char*)hc1 + aoff1 + ko, buf + 8192 + dst1);
        gload16((const char*)W0  + boff0 + ko, buf + 16384 + dst0);
        gload16((const char*)W0  + boff1 + ko, buf + 16384 + dst1);
        gload16((const char*)W1  + boff0 + ko, buf + 24576 + dst0);
        gload16((const char*)W1  + boff1 + ko, buf + 24576 + dst1);
    };

    stage(0, lds);
    __syncthreads();                          // vmcnt(0): buf0 ready
    int cur = 0;

    for (int kt = 0; kt < 16; ++kt) {
        char* buf = lds + cur * 32768;
        if (kt < 15) stage(kt + 1, lds + (cur ^ 1) * 32768);  // overlap w/ MFMA

#pragma unroll
        for (int kk = 0; kk < 2; ++kk) {
            const int col = kk * 64 + lq * 16;
            f16x8 af0[2], af1[2], bf0[2], bf1[2];
#pragma unroll
            for (int mi = 0; mi < 2; ++mi) {
                const int ad = swz(wr * 32 + mi * 16 + l16, col);
                af0[mi] = *(const f16x8*)(buf + ad);
                af1[mi] = *(const f16x8*)(buf + 8192 + ad);
            }
#pragma unroll
            for (int ni = 0; ni < 2; ++ni) {
                const int bd = swz(wc * 32 + ni * 16 + l16, col);
                bf0[ni] = *(const f16x8*)(buf + 16384 + bd);
                bf1[ni] = *(const f16x8*)(buf + 24576 + bd);
            }
#pragma unroll
            for (int mi = 0; mi < 2; ++mi)
#pragma unroll
                for (int ni = 0; ni < 2; ++ni)
                    acc0[mi][ni] = __builtin_amdgcn_mfma_f32_16x16x32_f16(
                        af0[mi], bf0[ni], acc0[mi][ni], 0, 0, 0);
#pragma unroll
            for (int mi = 0; mi < 2; ++mi)
#pragma unroll
                for (int ni = 0; ni < 2; ++ni)
                    accL[mi][ni] = __builtin_amdgcn_mfma_f32_16x16x32_f16(
                        af0[mi], bf1[ni], accL[mi][ni], 0, 0, 0);
#pragma unroll
            for (int mi = 0; mi < 2; ++mi)
#pragma unroll
                for (int ni = 0; ni < 2; ++ni)
                    accL[mi][ni] = __builtin_amdgcn_mfma_f32_16x16x32_f16(
                        af1[mi], bf0[ni], accL[mi][ni], 0, 0, 0);
        }
        if (kt < 15) {
            __syncthreads();                  // vmcnt(0): next buf ready; reads done
            cur ^= 1;
        }
    }

    // ---- epilogue ----
    if (nt >= 64) {                           // out_{t-1} tile
#pragma unroll
        for (int ni = 0; ni < 2; ++ni) {
            const int oc = (nt - 64) * 64 + wc * 32 + ni * 16 + l16;
            const float bias = bias_big[4096 + oc];
#pragma unroll
            for (int mi = 0; mi < 2; ++mi)
#pragma unroll
                for (int r = 0; r < 4; ++r) {
                    const int brow = mt * 64 + wr * 32 + mi * 16 + lq * 4 + r;
                    const float v = (acc0[mi][ni][r]
                                   + accL[mi][ni][r] * (1.f/2048.f)) * (1.f/16.f)
                                  + bias;
                    outp[(size_t)brow * 1024 + oc] = v;
                }
        }
        return;
    }
    // gate tile: fused GRU update
    const int gate = lane & 3;
#pragma unroll
    for (int ni = 0; ni < 2; ++ni) {
        const int c = nt * 64 + wc * 32 + ni * 16 + l16;   // 0..4095
        const int u = c >> 2;
        const int orig_n = gate * 1024 + u;
        const float bias = bias_big[orig_n];
        float w0 = 0.f, w1 = 0.f;
        if (gate < 3) { w0 = W_ih[(size_t)orig_n * 1026 + 1024];
                        w1 = W_ih[(size_t)orig_n * 1026 + 1025]; }
#pragma unroll
        for (int mi = 0; mi < 2; ++mi)
#pragma unroll
            for (int r = 0; r < 4; ++r) {
                const int brow = mt * 64 + wr * 32 + mi * 16 + lq * 4 + r;
                const float v = (acc0[mi][ni][r]
                               + accL[mi][ni][r] * (1.f/2048.f)) * (1.f/16.f)
                              + bias
                              + act[brow * 2] * w0 + act[brow * 2 + 1] * w1;
                const float o1 = __shfl_xor(v, 1);
                const float o2 = __shfl_xor(v, 2);
                const float o3 = __shfl_xor(v, 3);
                if (gate == 0) {
                    const float rr = 1.f / (1.f + expf(-v));
                    const float zz = 1.f / (1.f + expf(-o1));
                    const float nn = tanhf(o2 + rr * o3);
                    const size_t o = (size_t)brow * 1024 + u;
                    const float hnew = (1.f - zz) * nn + zz * h32[o];
                    h32[o] = hnew;
                    _Float16 a, b; split2h(hnew, a, b);
                    hn0[o] = a; hn1[o] = b;
                }
            }
    }
}

// ===========================================================================
// 128x64 3-term core (one-time t0 / wcomb kernels) — r11-verified, verbatim.
// ===========================================================================
__device__ __forceinline__ void stage_regs(
    const _Float16* __restrict__ A0, const _Float16* __restrict__ A1,
    const _Float16* __restrict__ B0, const _Float16* __restrict__ B1,
    int mrow0, int nrow0, int wid, int lr, int lc, int kt,
    f16x8 (&ra0)[4], f16x8 (&ra1)[4], f16x8 (&rb0)[2], f16x8 (&rb1)[2])
{
    const int koff = kt * 128 + lc;
    const char* a0 = (const char*)A0 + koff;
    const char* a1 = (const char*)A1 + koff;
    const char* b0 = (const char*)B0 + koff;
    const char* b1 = (const char*)B1 + koff;
#pragma unroll
    for (int j = 0; j < 4; ++j) {
        const size_t ro = (size_t)(mrow0 + wid * 32 + j * 8 + lr) * 2048;
        ra0[j] = *(const f16x8*)(a0 + ro);
        ra1[j] = *(const f16x8*)(a1 + ro);
    }
#pragma unroll
    for (int j = 0; j < 2; ++j) {
        const size_t ro = (size_t)(nrow0 + wid * 16 + j * 8 + lr) * 2048;
        rb0[j] = *(const f16x8*)(b0 + ro);
        rb1[j] = *(const f16x8*)(b1 + ro);
    }
}

__device__ __forceinline__ void gemm_core3t(
    const _Float16* __restrict__ A0, const _Float16* __restrict__ A1,
    const _Float16* __restrict__ B0, const _Float16* __restrict__ B1,
    int mrow0, int nrow0, char* lds,
    f32x4 (&acc0)[4][2], f32x4 (&accL)[4][2])
{
    const int tid  = threadIdx.x;
    const int wid  = tid >> 6;
    const int lane = tid & 63;
    const int wr = wid >> 1, wc = wid & 1;
    const int l16 = lane & 15, lq = lane >> 4;
    const int lr = lane >> 3, lc = (lane & 7) << 4;
    const int sw = lc ^ (lr << 4);

    f16x8 pa0[4], pa1[4], pb0[2], pb1[2];
    f16x8 na0[4], na1[4], nb0[2], nb1[2];
    stage_regs(A0, A1, B0, B1, mrow0, nrow0, wid, lr, lc, 0, pa0, pa1, pb0, pb1);

    for (int kt = 0; kt < 16; ++kt) {
        if (kt < 15)
            stage_regs(A0, A1, B0, B1, mrow0, nrow0, wid, lr, lc, kt + 1,
                       na0, na1, nb0, nb1);
        __syncthreads();
#pragma unroll
        for (int j = 0; j < 4; ++j) {
            const int ro = (wid * 32 + j * 8 + lr) * 128 + sw;
            *(f16x8*)(lds + ro)         = pa0[j];
            *(f16x8*)(lds + 16384 + ro) = pa1[j];
        }
#pragma unroll
        for (int j = 0; j < 2; ++j) {
            const int ro = (wid * 16 + j * 8 + lr) * 128 + sw;
            *(f16x8*)(lds + 32768 + ro) = pb0[j];
            *(f16x8*)(lds + 40960 + ro) = pb1[j];
        }
        __syncthreads();

#pragma unroll
        for (int kk = 0; kk < 2; ++kk) {
            const int col = kk * 64 + lq * 16;
            f16x8 af0[4], af1[4], bf0[2], bf1[2];
#pragma unroll
            for (int mi = 0; mi < 4; ++mi) {
                const int ad = swz(wr * 64 + mi * 16 + l16, col);
                af0[mi] = *(const f16x8*)(lds + ad);
                af1[mi] = *(const f16x8*)(lds + 16384 + ad);
            }
#pragma unroll
            for (int ni = 0; ni < 2; ++ni) {
                const int bd = swz(wc * 32 + ni * 16 + l16, col);
                bf0[ni] = *(const f16x8*)(lds + 32768 + bd);
                bf1[ni] = *(const f16x8*)(lds + 40960 + bd);
            }
#pragma unroll
            for (int mi = 0; mi < 4; ++mi)
#pragma unroll
                for (int ni = 0; ni < 2; ++ni)
                    acc0[mi][ni] = __builtin_amdgcn_mfma_f32_16x16x32_f16(
                        af0[mi], bf0[ni], acc0[mi][ni], 0, 0, 0);
#pragma unroll
            for (int mi = 0; mi < 4; ++mi)
#pragma unroll
                for (int ni = 0; ni < 2; ++ni)
                    accL[mi][ni] = __builtin_amdgcn_mfma_f32_16x16x32_f16(
                        af0[mi], bf1[ni], accL[mi][ni], 0, 0, 0);
#pragma unroll
            for (int mi = 0; mi < 4; ++mi)
#pragma unroll
                for (int ni = 0; ni < 2; ++ni)
                    accL[mi][ni] = __builtin_amdgcn_mfma_f32_16x16x32_f16(
                        af1[mi], bf0[ni], accL[mi][ni], 0, 0, 0);
        }
        if (kt < 15) {
#pragma unroll
            for (int j = 0; j < 4; ++j) { pa0[j] = na0[j]; pa1[j] = na1[j]; }
#pragma unroll
            for (int j = 0; j < 2; ++j) { pb0[j] = nb0[j]; pb1[j] = nb1[j]; }
        }
    }
}

// ---------------------------------------------------------------------------
// t=0 GEMM: nt<48 -> gi = enc @ Wih^T ; nt>=48 -> gh = h0 @ Whh^T.
// ---------------------------------------------------------------------------
__global__ __launch_bounds__(256) void gemm_t0_16(
    const _Float16* __restrict__ e0, const _Float16* __restrict__ e1,
    const _Float16* __restrict__ hA0, const _Float16* __restrict__ hA1,
    const _Float16* __restrict__ Wih0, const _Float16* __restrict__ Wih1,
    const _Float16* __restrict__ Whh0, const _Float16* __restrict__ Whh1,
    const float* __restrict__ W_ih,
    const float* __restrict__ b_ih, const float* __restrict__ b_hh,
    const float* __restrict__ act,
    float* __restrict__ gbuf)
{
    __shared__ alignas(16) char lds[49152];
    const int bid = blockIdx.x;
    const int mt = bid & 3, nt = bid >> 2;      // nt 0..95
    const _Float16 *A0, *A1, *B0, *B1; int nr0;
    if (nt < 48) { A0 = e0;  A1 = e1;  B0 = Wih0; B1 = Wih1; nr0 = nt * 64; }
    else         { A0 = hA0; A1 = hA1; B0 = Whh0; B1 = Whh1; nr0 = (nt - 48) * 64; }
    f32x4 acc0[4][2] = {}, accL[4][2] = {};
    gemm_core3t(A0, A1, B0, B1, mt * 128, nr0, lds, acc0, accL);

    const int lane = threadIdx.x & 63, wid = threadIdx.x >> 6;
    const int wr = wid >> 1, wc = wid & 1, l16 = lane & 15, lq = lane >> 4;
#pragma unroll
    for (int ni = 0; ni < 2; ++ni) {
        const int ncol = nt * 64 + wc * 32 + ni * 16 + l16;   // 0..6143
        float bias, w0 = 0.f, w1 = 0.f;
        if (ncol < 3072) {
            bias = b_ih[ncol];
            w0 = W_ih[(size_t)ncol * 1026 + 1024];
            w1 = W_ih[(size_t)ncol * 1026 + 1025];
        } else bias = b_hh[ncol - 3072];
#pragma unroll
        for (int mi = 0; mi < 4; ++mi)
#pragma unroll
            for (int r = 0; r < 4; ++r) {
                const int brow = mt * 128 + wr * 64 + mi * 16 + lq * 4 + r;
                const float v = (acc0[mi][ni][r]
                               + accL[mi][ni][r] * (1.f/2048.f)) * (1.f/16.f)
                              + bias
                              + act[brow * 2] * w0 + act[brow * 2 + 1] * w1;
                gbuf[(size_t)brow * 6144 + ncol] = v;
            }
    }
}

// ---------------------------------------------------------------------------
// W_comb on the f16 core; rows<2048 add W_hh; interleaved rows 4u+g.
// ---------------------------------------------------------------------------
__global__ __launch_bounds__(256) void gemm_wcomb16(
    const _Float16* __restrict__ Wih0, const _Float16* __restrict__ Wih1,
    const _Float16* __restrict__ WoT0, const _Float16* __restrict__ WoT1,
    const float* __restrict__ W_hh,
    _Float16* __restrict__ W0, _Float16* __restrict__ W1)
{
    __shared__ alignas(16) char lds[49152];
    const int bid = blockIdx.x;
    const int mt = bid >> 4, nt = bid & 15;
    f32x4 acc0[4][2] = {}, accL[4][2] = {};
    gemm_core3t(Wih0, Wih1, WoT0, WoT1, mt * 128, nt * 64, lds, acc0, accL);

    const int lane = threadIdx.x & 63, wid = threadIdx.x >> 6;
    const int wr = wid >> 1, wc = wid & 1, l16 = lane & 15, lq = lane >> 4;
#pragma unroll
    for (int ni = 0; ni < 2; ++ni) {
        const int c = nt * 64 + wc * 32 + ni * 16 + l16;       // 0..1023
#pragma unroll
        for (int mi = 0; mi < 4; ++mi)
#pragma unroll
            for (int r = 0; r < 4; ++r) {
                const int i = mt * 128 + wr * 64 + mi * 16 + lq * 4 + r; // 0..3071
                float v = (acc0[mi][ni][r]
                         + accL[mi][ni][r] * (1.f/2048.f)) * (1.f/256.f);
                if (i < 2048) v += W_hh[(size_t)i * 1024 + c];
                const size_t nr = (size_t)(4 * (i & 1023) + (i >> 10)) * 1024 + c;
                _Float16 a, b; split2h(v * 16.0f, a, b);
                W0[nr] = a; W1[nr] = b;
            }
    }
}

// ---------------------------------------------------------------------------
__global__ __launch_bounds__(256) void ew_t0_16(
    const float* __restrict__ gbuf, float* __restrict__ h32,
    _Float16* __restrict__ hA0, _Float16* __restrict__ hA1)
{
    const int idx = blockIdx.x * 256 + threadIdx.x;   // 0..524287
    const int b = idx >> 10, j = idx & 1023;
    const float* g = gbuf + (size_t)b * 6144;
    const float pr  = g[j]        + g[3072 + j];
    const float pz  = g[1024 + j] + g[4096 + j];
    const float r = 1.f / (1.f + expf(-pr));
    const float z = 1.f / (1.f + expf(-pz));
    const float n = tanhf(g[2048 + j] + r * g[5120 + j]);
    const float h = (1.f - z) * n + z * h32[idx];
    h32[idx] = h;
    split2h(h, hA0[idx], hA1[idx]);
}

__global__ __launch_bounds__(256) void prep_w16(
    const float* __restrict__ W_ih, const float* __restrict__ W_hh,
    const float* __restrict__ W_out,
    _Float16* __restrict__ Wih0, _Float16* __restrict__ Wih1,
    _Float16* __restrict__ Whh0, _Float16* __restrict__ Whh1,
    _Float16* __restrict__ WoT0, _Float16* __restrict__ WoT1,
    _Float16* __restrict__ W0,   _Float16* __restrict__ W1)
{
    const int idx = blockIdx.x * 256 + threadIdx.x;   // < 3072*1024
    const int n = idx >> 10, k = idx & 1023;
    _Float16 a, b;
    split2h(W_ih[(size_t)n * 1026 + k] * 16.0f, a, b);
    Wih0[idx] = a; Wih1[idx] = b;
    split2h(W_hh[idx] * 16.0f, a, b);
    Whh0[idx] = a; Whh1[idx] = b;
    if (n >= 2048) {                         // gh_n -> interleaved row 4u+3
        const size_t nr = (size_t)(4 * (n - 2048) + 3) * 1024 + k;
        W0[nr] = a; W1[nr] = b;
    }
    if (n < 1024) {                          // W_out rows [4096,5120) + transpose
        split2h(W_out[idx] * 16.0f, a, b);
        W0[(size_t)(4096 + n) * 1024 + k] = a;
        W1[(size_t)(4096 + n) * 1024 + k] = b;
        WoT0[(size_t)k * 1024 + n] = a;
        WoT1[(size_t)k * 1024 + n] = b;
    }
}

__global__ __launch_bounds__(256) void prep_m16(
    const float* __restrict__ enc, const float* __restrict__ h0,
    const float* __restrict__ W_ih,
    const float* __restrict__ b_ih, const float* __restrict__ b_hh,
    const float* __restrict__ b_out,
    _Float16* __restrict__ e0, _Float16* __restrict__ e1,
    _Float16* __restrict__ hA0, _Float16* __restrict__ hA1,
    float* __restrict__ h32, float* __restrict__ bias_big)
{
    const int idx = blockIdx.x * 256 + threadIdx.x;
    if (idx < 524288) {
        split2h(enc[idx], e0[idx], e1[idx]);
        const float hv = h0[idx];
        h32[idx] = hv;
        split2h(hv, hA0[idx], hA1[idx]);
    } else if (idx < 524288 + 5120) {
        const int nn = idx - 524288;
        float v;
        if (nn < 3072) {
            float d = 0.f;
            for (int o = 0; o < 1024; ++o) d += W_ih[(size_t)nn * 1026 + o] * b_out[o];
            v = b_ih[nn] + d + (nn < 2048 ? b_hh[nn] : 0.f);
        } else if (nn < 4096) v = b_hh[nn - 1024];
        else                  v = b_out[nn - 4096];
        bias_big[nn] = v;
    }
}

// ===========================================================================
// fp32 fallback (round-3 verified) for small ws_size.
// ===========================================================================
__global__ __launch_bounds__(256) void gemm_f32(
    const float* __restrict__ A, int lda,
    const float* __restrict__ Bm, int ldb,
    const float* __restrict__ bias,
    const float* __restrict__ act,
    float* __restrict__ dst, int dst_stride, int dst_coloff)
{
    __shared__ float As[16][64];
    __shared__ float Bs[16][64];
    const int t  = threadIdx.x;
    const int tx = t & 15, ty = t >> 4;
    const int row0 = blockIdx.y * 64, col0 = blockIdx.x * 64;
    const int lm = t >> 2;
    const int lk = (t & 3) * 4;
    float acc[4][4] = {};
    for (int kt = 0; kt < 64; ++kt) {
        const int kbase = kt * 16 + lk;
        const float* ap = A + (size_t)(row0 + lm) * lda + kbase;
        const float a0 = ap[0], a1 = ap[1], a2 = ap[2], a3 = ap[3];
        const float* bp = Bm + (size_t)(col0 + lm) * ldb + kbase;
        const float b0 = bp[0], b1 = bp[1], b2 = bp[2], b3 = bp[3];
        __syncthreads();
        As[lk + 0][lm] = a0;   As[lk + 1][lm] = a1;
        As[lk + 2][lm] = a2;   As[lk + 3][lm] = a3;
        Bs[lk + 0][lm] = b0;   Bs[lk + 1][lm] = b1;
        Bs[lk + 2][lm] = b2;   Bs[lk + 3][lm] = b3;
        __syncthreads();
#pragma unroll
        for (int kk = 0; kk < 16; ++kk) {
            const f32x4 a4 = *(const f32x4*)&As[kk][ty * 4];
            const f32x4 b4 = *(const f32x4*)&Bs[kk][tx * 4];
#pragma unroll
            for (int i = 0; i < 4; ++i)
#pragma unroll
                for (int j = 0; j < 4; ++j)
                    acc[i][j] += a4[i] * b4[j];
        }
    }
#pragma unroll
    for (int i = 0; i < 4; ++i) {
        const int row = row0 + ty * 4 + i;
        float a0 = 0.f, a1 = 0.f;
        if (act) { a0 = act[row * 2]; a1 = act[row * 2 + 1]; }
#pragma unroll
        for (int j = 0; j < 4; ++j) {
            const int col = col0 + tx * 4 + j;
            float v = acc[i][j] + (bias ? bias[col] : 0.f);
            if (act) v += a0 * Bm[(size_t)col * ldb + 1024]
                        + a1 * Bm[(size_t)col * ldb + 1025];
            dst[(size_t)row * dst_stride + dst_coloff + col] = v;
        }
    }
}

__global__ __launch_bounds__(256) void ew_gru32(
    const float* __restrict__ gbuf, float* __restrict__ h32)
{
    const int idx = blockIdx.x * 256 + threadIdx.x;
    const int b = idx >> 10, j = idx & 1023;
    const float* g = gbuf + (size_t)b * 6144;
    const float pr  = g[j]        + g[3072 + j];
    const float pz  = g[1024 + j] + g[4096 + j];
    const float r = 1.f / (1.f + expf(-pr));
    const float z = 1.f / (1.f + expf(-pz));
    const float n = tanhf(g[2048 + j] + r * g[5120 + j]);
    h32[idx] = (1.f - z) * n + z * h32[idx];
}

__global__ __launch_bounds__(256) void init_h(const float* __restrict__ h0,
                                              float* __restrict__ h32) {
    const int idx = blockIdx.x * 256 + threadIdx.x;
    h32[idx] = h0[idx];
}

// ---------------------------------------------------------------------------
extern "C" void kernel_launch(void* const* d_in, const int* in_sizes, int n_in,
                              void* d_out, int out_size, void* d_ws, size_t ws_size,
                              hipStream_t stream) {
    const float* enc     = (const float*)d_in[0];
    const float* actions = (const float*)d_in[1];   // [64][512][2]
    const float* h0      = (const float*)d_in[2];
    const float* W_ih    = (const float*)d_in[3];   // [3072][1026]
    const float* W_hh    = (const float*)d_in[4];   // [3072][1024]
    const float* b_ih    = (const float*)d_in[5];
    const float* b_hh    = (const float*)d_in[6];
    const float* W_out   = (const float*)d_in[7];   // [1024][1024]
    const float* b_out   = (const float*)d_in[8];
    float* out = (float*)d_out;                     // [64][512][1024]
    char* ws = (char*)d_ws;

    float* h32  = (float*)ws;                       // 2,097,152 B
    float* gbuf = (float*)(ws + 2097152);           // 12,582,912 -> 14,680,064

    const size_t NEED = 69226496;                   // == r7-proven available
    if (ws_size < NEED) {
        // ---------------- fp32 fallback (round-3 verified) ----------------
        init_h<<<2048, 256, 0, stream>>>(h0, h32);
        const float* e = enc;
        for (int t = 0; t < 64; ++t) {
            gemm_f32<<<dim3(48, 8), 256, 0, stream>>>(
                e, 1024, W_ih, 1026, b_ih, actions + (size_t)t * 1024, gbuf, 6144, 0);
            gemm_f32<<<dim3(48, 8), 256, 0, stream>>>(
                h32, 1024, W_hh, 1024, b_hh, nullptr, gbuf, 6144, 3072);
            ew_gru32<<<2048, 256, 0, stream>>>(gbuf, h32);
            float* ot = out + (size_t)t * 524288;
            gemm_f32<<<dim3(16, 8), 256, 0, stream>>>(
                h32, 1024, W_out, 1024, b_out, nullptr, ot, 1024, 0);
            e = ot;
        }
        return;
    }

    // ---------------- f16 2-plane fused MFMA path ----------------
    size_t off = 14680064;
    auto take = [&](size_t bytes) { char* p = ws + off; off += bytes; return p; };
    _Float16* W0   = (_Float16*)take(10485760);   // interleaved Wbig 5120x1024
    _Float16* W1   = (_Float16*)take(10485760);
    _Float16* Wih0 = (_Float16*)take(6291456);    // 3072x1024 (t0 / wcomb only)
    _Float16* Wih1 = (_Float16*)take(6291456);
    _Float16* Whh0 = (_Float16*)take(6291456);
    _Float16* Whh1 = (_Float16*)take(6291456);
    _Float16* WoT0 = (_Float16*)take(2097152);    // 1024x1024 (wcomb only)
    _Float16* WoT1 = (_Float16*)take(2097152);
    _Float16* e0   = (_Float16*)take(1048576);    // 512x1024
    _Float16* e1   = (_Float16*)take(1048576);
    _Float16* hA0  = (_Float16*)take(1048576);
    _Float16* hA1  = (_Float16*)take(1048576);
    float* bias_big= (float*)take(20480);         // 5120 f32
    // off == 69,226,496
    // h double-buffer B aliased into gbuf (gbuf dead after ew_t0_16):
    _Float16* hB0 = (_Float16*)gbuf;
    _Float16* hB1 = (_Float16*)((char*)gbuf + 1048576);

    prep_w16<<<12288, 256, 0, stream>>>(W_ih, W_hh, W_out,
        Wih0, Wih1, Whh0, Whh1, WoT0, WoT1, W0, W1);
    prep_m16<<<2068, 256, 0, stream>>>(enc, h0, W_ih, b_ih, b_hh, b_out,
        e0, e1, hA0, hA1, h32, bias_big);
    gemm_wcomb16<<<384, 256, 0, stream>>>(Wih0, Wih1, WoT0, WoT1, W_hh, W0, W1);

    // t = 0 (e = enc), then h_1 -> hA.
    gemm_t0_16<<<384, 256, 0, stream>>>(e0, e1, hA0, hA1,
        Wih0, Wih1, Whh0, Whh1, W_ih, b_ih, b_hh, actions, gbuf);
    ew_t0_16<<<2048, 256, 0, stream>>>(gbuf, h32, hA0, hA1);

    // t = 1..63: one fused kernel per step; then final out-only dispatch.
    _Float16 *c0 = hA0, *c1 = hA1, *n0 = hB0, *n1 = hB1;
    for (int t = 1; t < 64; ++t) {
        gemm_step64<<<640, 256, 0, stream>>>(c0, c1, W0, W1, n0, n1, h32,
            out + (size_t)(t - 1) * 524288, bias_big, W_ih,
            actions + (size_t)t * 1024, 0);
        _Float16* s;
        s = c0; c0 = n0; n0 = s;
        s = c1; c1 = n1; n1 = s;
    }
    gemm_step64<<<128, 256, 0, stream>>>(c0, c1, W0, W1, n0, n1, h32,
        out + (size_t)63 * 524288, bias_big, W_ih, actions, 1);
}

// Round 16
// 2010.166 us; speedup vs baseline: 1.3191x; 1.3191x over previous
//
#include <hip/hip_runtime.h>
#include <stdint.h>
#include <stddef.h>

// RNNPredictorBurnin — round 16: REVERT to round-14 exactly (2009 µs, PASS).
// r15's 2-phase dbuf regressed (+32%): __syncthreads' vmcnt(0) drain defeats
// source-level prefetch (m97-ceiling mechanism) while 64KB LDS halved
// co-residency 2.5->2 blocks/CU. r14's mechanism = TLP (640 blocks, 32KB LDS)
// + global_load_lds w=16 staging + fused GRU epilogue + folded W_comb.
// Math: f16 2-plane scaled split, 3 terms (~2^-22), fp32 master h.

typedef _Float16 f16x8 __attribute__((ext_vector_type(8)));
typedef float f32x4  __attribute__((ext_vector_type(4)));

__device__ __forceinline__ void split2h(float v, _Float16& a, _Float16& b) {
    a = (_Float16)v;
    b = (_Float16)((v - (float)a) * 2048.0f);
}

__device__ __forceinline__ int swz(int row, int col) {   // LDS byte address
    return row * 128 + (col ^ ((row & 7) << 4));
}

__device__ __forceinline__ void gload16(const char* src, char* ldsdst) {
    __builtin_amdgcn_global_load_lds(
        (const __attribute__((address_space(1))) void*)src,
        (__attribute__((address_space(3))) void*)ldsdst, 16, 0, 0);
}

// ===========================================================================
// Step kernel: 64x64 tile, 4 waves, 32KB LDS (A0@0 A1@8K B0@16K B1@24K).
// Staging: 8 global_load_lds per wave per kt (1KB each), linear LDS dest +
// inverse-swizzled per-lane source (rule #21; r4==r5 bit-identity verified);
// reads use swz(). Grid: steps 640 = 8 XCD x (8 mt x 10 nt); final 128.
// ===========================================================================
__global__ __launch_bounds__(256) void gemm_step64(
    const _Float16* __restrict__ hc0, const _Float16* __restrict__ hc1,
    const _Float16* __restrict__ W0,  const _Float16* __restrict__ W1,
    _Float16* __restrict__ hn0, _Float16* __restrict__ hn1,
    float* __restrict__ h32,
    float* __restrict__ outp,
    const float* __restrict__ bias_big,
    const float* __restrict__ W_ih,
    const float* __restrict__ act,
    int is_final)
{
    __shared__ alignas(16) char lds[32768];
    const int bid = blockIdx.x;
    int mt, nt;
    if (is_final) { mt = bid & 7; nt = 64 + (bid >> 3); }       // 128 blocks
    else { const int xcd = bid & 7, loc = bid >> 3;             // 640 blocks
           mt = loc & 7; nt = xcd * 10 + (loc >> 3); }          // nt 0..79
    const int nrow0 = (nt < 64) ? nt * 64 : 4096 + (nt - 64) * 64;

    const int tid  = threadIdx.x;
    const int wid  = tid >> 6;
    const int lane = tid & 63;
    const int wr = wid >> 1, wc = wid & 1;
    const int l16 = lane & 15, lq = lane >> 4;
    const int srcsw = (((lane & 7) ^ ((lane >> 3) & 7)) << 4);
    const int lrow = lane >> 3;

    // Per-lane global byte offsets (row part), constant across kt:
    const size_t aoff0 = (size_t)(mt * 64 + wid * 16 + lrow) * 2048 + srcsw;
    const size_t aoff1 = aoff0 + 8 * 2048;
    const size_t boff0 = (size_t)(nrow0 + wid * 16 + lrow) * 2048 + srcsw;
    const size_t boff1 = boff0 + 8 * 2048;
    const int dst0 = (wid * 16) * 128;          // wave-uniform LDS bases
    const int dst1 = (wid * 16 + 8) * 128;

    f32x4 acc0[2][2] = {}, accL[2][2] = {};

    for (int kt = 0; kt < 16; ++kt) {
        const int ko = kt * 128;
        gload16((const char*)hc0 + aoff0 + ko, lds + dst0);
        gload16((const char*)hc0 + aoff1 + ko, lds + dst1);
        gload16((const char*)hc1 + aoff0 + ko, lds + 8192 + dst0);
        gload16((const char*)hc1 + aoff1 + ko, lds + 8192 + dst1);
        gload16((const char*)W0  + boff0 + ko, lds + 16384 + dst0);
        gload16((const char*)W0  + boff1 + ko, lds + 16384 + dst1);
        gload16((const char*)W1  + boff0 + ko, lds + 24576 + dst0);
        gload16((const char*)W1  + boff1 + ko, lds + 24576 + dst1);
        __syncthreads();                      // drains vmcnt before reads

#pragma unroll
        for (int kk = 0; kk < 2; ++kk) {
            const int col = kk * 64 + lq * 16;
            f16x8 af0[2], af1[2], bf0[2], bf1[2];
#pragma unroll
            for (int mi = 0; mi < 2; ++mi) {
                const int ad = swz(wr * 32 + mi * 16 + l16, col);
                af0[mi] = *(const f16x8*)(lds + ad);
                af1[mi] = *(const f16x8*)(lds + 8192 + ad);
            }
#pragma unroll
            for (int ni = 0; ni < 2; ++ni) {
                const int bd = swz(wc * 32 + ni * 16 + l16, col);
                bf0[ni] = *(const f16x8*)(lds + 16384 + bd);
                bf1[ni] = *(const f16x8*)(lds + 24576 + bd);
            }
#pragma unroll
            for (int mi = 0; mi < 2; ++mi)
#pragma unroll
                for (int ni = 0; ni < 2; ++ni)
                    acc0[mi][ni] = __builtin_amdgcn_mfma_f32_16x16x32_f16(
                        af0[mi], bf0[ni], acc0[mi][ni], 0, 0, 0);
#pragma unroll
            for (int mi = 0; mi < 2; ++mi)
#pragma unroll
                for (int ni = 0; ni < 2; ++ni)
                    accL[mi][ni] = __builtin_amdgcn_mfma_f32_16x16x32_f16(
                        af0[mi], bf1[ni], accL[mi][ni], 0, 0, 0);
#pragma unroll
            for (int mi = 0; mi < 2; ++mi)
#pragma unroll
                for (int ni = 0; ni < 2; ++ni)
                    accL[mi][ni] = __builtin_amdgcn_mfma_f32_16x16x32_f16(
                        af1[mi], bf0[ni], accL[mi][ni], 0, 0, 0);
        }
        __syncthreads();                      // reads done before next stage
    }

    // ---- epilogue ----
    if (nt >= 64) {                           // out_{t-1} tile
#pragma unroll
        for (int ni = 0; ni < 2; ++ni) {
            const int oc = (nt - 64) * 64 + wc * 32 + ni * 16 + l16;
            const float bias = bias_big[4096 + oc];
#pragma unroll
            for (int mi = 0; mi < 2; ++mi)
#pragma unroll
                for (int r = 0; r < 4; ++r) {
                    const int brow = mt * 64 + wr * 32 + mi * 16 + lq * 4 + r;
                    const float v = (acc0[mi][ni][r]
                                   + accL[mi][ni][r] * (1.f/2048.f)) * (1.f/16.f)
                                  + bias;
                    outp[(size_t)brow * 1024 + oc] = v;
                }
        }
        return;
    }
    // gate tile: fused GRU update
    const int gate = lane & 3;
#pragma unroll
    for (int ni = 0; ni < 2; ++ni) {
        const int c = nt * 64 + wc * 32 + ni * 16 + l16;   // 0..4095
        const int u = c >> 2;
        const int orig_n = gate * 1024 + u;
        const float bias = bias_big[orig_n];
        float w0 = 0.f, w1 = 0.f;
        if (gate < 3) { w0 = W_ih[(size_t)orig_n * 1026 + 1024];
                        w1 = W_ih[(size_t)orig_n * 1026 + 1025]; }
#pragma unroll
        for (int mi = 0; mi < 2; ++mi)
#pragma unroll
            for (int r = 0; r < 4; ++r) {
                const int brow = mt * 64 + wr * 32 + mi * 16 + lq * 4 + r;
                const float v = (acc0[mi][ni][r]
                               + accL[mi][ni][r] * (1.f/2048.f)) * (1.f/16.f)
                              + bias
                              + act[brow * 2] * w0 + act[brow * 2 + 1] * w1;
                const float o1 = __shfl_xor(v, 1);
                const float o2 = __shfl_xor(v, 2);
                const float o3 = __shfl_xor(v, 3);
                if (gate == 0) {
                    const float rr = 1.f / (1.f + expf(-v));
                    const float zz = 1.f / (1.f + expf(-o1));
                    const float nn = tanhf(o2 + rr * o3);
                    const size_t o = (size_t)brow * 1024 + u;
                    const float hnew = (1.f - zz) * nn + zz * h32[o];
                    h32[o] = hnew;
                    _Float16 a, b; split2h(hnew, a, b);
                    hn0[o] = a; hn1[o] = b;
                }
            }
    }
}

// ===========================================================================
// 128x64 3-term core (one-time t0 / wcomb kernels) — r11-verified, verbatim.
// ===========================================================================
__device__ __forceinline__ void stage_regs(
    const _Float16* __restrict__ A0, const _Float16* __restrict__ A1,
    const _Float16* __restrict__ B0, const _Float16* __restrict__ B1,
    int mrow0, int nrow0, int wid, int lr, int lc, int kt,
    f16x8 (&ra0)[4], f16x8 (&ra1)[4], f16x8 (&rb0)[2], f16x8 (&rb1)[2])
{
    const int koff = kt * 128 + lc;
    const char* a0 = (const char*)A0 + koff;
    const char* a1 = (const char*)A1 + koff;
    const char* b0 = (const char*)B0 + koff;
    const char* b1 = (const char*)B1 + koff;
#pragma unroll
    for (int j = 0; j < 4; ++j) {
        const size_t ro = (size_t)(mrow0 + wid * 32 + j * 8 + lr) * 2048;
        ra0[j] = *(const f16x8*)(a0 + ro);
        ra1[j] = *(const f16x8*)(a1 + ro);
    }
#pragma unroll
    for (int j = 0; j < 2; ++j) {
        const size_t ro = (size_t)(nrow0 + wid * 16 + j * 8 + lr) * 2048;
        rb0[j] = *(const f16x8*)(b0 + ro);
        rb1[j] = *(const f16x8*)(b1 + ro);
    }
}

__device__ __forceinline__ void gemm_core3t(
    const _Float16* __restrict__ A0, const _Float16* __restrict__ A1,
    const _Float16* __restrict__ B0, const _Float16* __restrict__ B1,
    int mrow0, int nrow0, char* lds,
    f32x4 (&acc0)[4][2], f32x4 (&accL)[4][2])
{
    const int tid  = threadIdx.x;
    const int wid  = tid >> 6;
    const int lane = tid & 63;
    const int wr = wid >> 1, wc = wid & 1;
    const int l16 = lane & 15, lq = lane >> 4;
    const int lr = lane >> 3, lc = (lane & 7) << 4;
    const int sw = lc ^ (lr << 4);

    f16x8 pa0[4], pa1[4], pb0[2], pb1[2];
    f16x8 na0[4], na1[4], nb0[2], nb1[2];
    stage_regs(A0, A1, B0, B1, mrow0, nrow0, wid, lr, lc, 0, pa0, pa1, pb0, pb1);

    for (int kt = 0; kt < 16; ++kt) {
        if (kt < 15)
            stage_regs(A0, A1, B0, B1, mrow0, nrow0, wid, lr, lc, kt + 1,
                       na0, na1, nb0, nb1);
        __syncthreads();
#pragma unroll
        for (int j = 0; j < 4; ++j) {
            const int ro = (wid * 32 + j * 8 + lr) * 128 + sw;
            *(f16x8*)(lds + ro)         = pa0[j];
            *(f16x8*)(lds + 16384 + ro) = pa1[j];
        }
#pragma unroll
        for (int j = 0; j < 2; ++j) {
            const int ro = (wid * 16 + j * 8 + lr) * 128 + sw;
            *(f16x8*)(lds + 32768 + ro) = pb0[j];
            *(f16x8*)(lds + 40960 + ro) = pb1[j];
        }
        __syncthreads();

#pragma unroll
        for (int kk = 0; kk < 2; ++kk) {
            const int col = kk * 64 + lq * 16;
            f16x8 af0[4], af1[4], bf0[2], bf1[2];
#pragma unroll
            for (int mi = 0; mi < 4; ++mi) {
                const int ad = swz(wr * 64 + mi * 16 + l16, col);
                af0[mi] = *(const f16x8*)(lds + ad);
                af1[mi] = *(const f16x8*)(lds + 16384 + ad);
            }
#pragma unroll
            for (int ni = 0; ni < 2; ++ni) {
                const int bd = swz(wc * 32 + ni * 16 + l16, col);
                bf0[ni] = *(const f16x8*)(lds + 32768 + bd);
                bf1[ni] = *(const f16x8*)(lds + 40960 + bd);
            }
#pragma unroll
            for (int mi = 0; mi < 4; ++mi)
#pragma unroll
                for (int ni = 0; ni < 2; ++ni)
                    acc0[mi][ni] = __builtin_amdgcn_mfma_f32_16x16x32_f16(
                        af0[mi], bf0[ni], acc0[mi][ni], 0, 0, 0);
#pragma unroll
            for (int mi = 0; mi < 4; ++mi)
#pragma unroll
                for (int ni = 0; ni < 2; ++ni)
                    accL[mi][ni] = __builtin_amdgcn_mfma_f32_16x16x32_f16(
                        af0[mi], bf1[ni], accL[mi][ni], 0, 0, 0);
#pragma unroll
            for (int mi = 0; mi < 4; ++mi)
#pragma unroll
                for (int ni = 0; ni < 2; ++ni)
                    accL[mi][ni] = __builtin_amdgcn_mfma_f32_16x16x32_f16(
                        af1[mi], bf0[ni], accL[mi][ni], 0, 0, 0);
        }
        if (kt < 15) {
#pragma unroll
            for (int j = 0; j < 4; ++j) { pa0[j] = na0[j]; pa1[j] = na1[j]; }
#pragma unroll
            for (int j = 0; j < 2; ++j) { pb0[j] = nb0[j]; pb1[j] = nb1[j]; }
        }
    }
}

// ---------------------------------------------------------------------------
// t=0 GEMM: nt<48 -> gi = enc @ Wih^T ; nt>=48 -> gh = h0 @ Whh^T.
// ---------------------------------------------------------------------------
__global__ __launch_bounds__(256) void gemm_t0_16(
    const _Float16* __restrict__ e0, const _Float16* __restrict__ e1,
    const _Float16* __restrict__ hA0, const _Float16* __restrict__ hA1,
    const _Float16* __restrict__ Wih0, const _Float16* __restrict__ Wih1,
    const _Float16* __restrict__ Whh0, const _Float16* __restrict__ Whh1,
    const float* __restrict__ W_ih,
    const float* __restrict__ b_ih, const float* __restrict__ b_hh,
    const float* __restrict__ act,
    float* __restrict__ gbuf)
{
    __shared__ alignas(16) char lds[49152];
    const int bid = blockIdx.x;
    const int mt = bid & 3, nt = bid >> 2;      // nt 0..95
    const _Float16 *A0, *A1, *B0, *B1; int nr0;
    if (nt < 48) { A0 = e0;  A1 = e1;  B0 = Wih0; B1 = Wih1; nr0 = nt * 64; }
    else         { A0 = hA0; A1 = hA1; B0 = Whh0; B1 = Whh1; nr0 = (nt - 48) * 64; }
    f32x4 acc0[4][2] = {}, accL[4][2] = {};
    gemm_core3t(A0, A1, B0, B1, mt * 128, nr0, lds, acc0, accL);

    const int lane = threadIdx.x & 63, wid = threadIdx.x >> 6;
    const int wr = wid >> 1, wc = wid & 1, l16 = lane & 15, lq = lane >> 4;
#pragma unroll
    for (int ni = 0; ni < 2; ++ni) {
        const int ncol = nt * 64 + wc * 32 + ni * 16 + l16;   // 0..6143
        float bias, w0 = 0.f, w1 = 0.f;
        if (ncol < 3072) {
            bias = b_ih[ncol];
            w0 = W_ih[(size_t)ncol * 1026 + 1024];
            w1 = W_ih[(size_t)ncol * 1026 + 1025];
        } else bias = b_hh[ncol - 3072];
#pragma unroll
        for (int mi = 0; mi < 4; ++mi)
#pragma unroll
            for (int r = 0; r < 4; ++r) {
                const int brow = mt * 128 + wr * 64 + mi * 16 + lq * 4 + r;
                const float v = (acc0[mi][ni][r]
                               + accL[mi][ni][r] * (1.f/2048.f)) * (1.f/16.f)
                              + bias
                              + act[brow * 2] * w0 + act[brow * 2 + 1] * w1;
                gbuf[(size_t)brow * 6144 + ncol] = v;
            }
    }
}

// ---------------------------------------------------------------------------
// W_comb on the f16 core; rows<2048 add W_hh; interleaved rows 4u+g.
// ---------------------------------------------------------------------------
__global__ __launch_bounds__(256) void gemm_wcomb16(
    const _Float16* __restrict__ Wih0, const _Float16* __restrict__ Wih1,
    const _Float16* __restrict__ WoT0, const _Float16* __restrict__ WoT1,
    const float* __restrict__ W_hh,
    _Float16* __restrict__ W0, _Float16* __restrict__ W1)
{
    __shared__ alignas(16) char lds[49152];
    const int bid = blockIdx.x;
    const int mt = bid >> 4, nt = bid & 15;
    f32x4 acc0[4][2] = {}, accL[4][2] = {};
    gemm_core3t(Wih0, Wih1, WoT0, WoT1, mt * 128, nt * 64, lds, acc0, accL);

    const int lane = threadIdx.x & 63, wid = threadIdx.x >> 6;
    const int wr = wid >> 1, wc = wid & 1, l16 = lane & 15, lq = lane >> 4;
#pragma unroll
    for (int ni = 0; ni < 2; ++ni) {
        const int c = nt * 64 + wc * 32 + ni * 16 + l16;       // 0..1023
#pragma unroll
        for (int mi = 0; mi < 4; ++mi)
#pragma unroll
            for (int r = 0; r < 4; ++r) {
                const int i = mt * 128 + wr * 64 + mi * 16 + lq * 4 + r; // 0..3071
                float v = (acc0[mi][ni][r]
                         + accL[mi][ni][r] * (1.f/2048.f)) * (1.f/256.f);
                if (i < 2048) v += W_hh[(size_t)i * 1024 + c];
                const size_t nr = (size_t)(4 * (i & 1023) + (i >> 10)) * 1024 + c;
                _Float16 a, b; split2h(v * 16.0f, a, b);
                W0[nr] = a; W1[nr] = b;
            }
    }
}

// ---------------------------------------------------------------------------
__global__ __launch_bounds__(256) void ew_t0_16(
    const float* __restrict__ gbuf, float* __restrict__ h32,
    _Float16* __restrict__ hA0, _Float16* __restrict__ hA1)
{
    const int idx = blockIdx.x * 256 + threadIdx.x;   // 0..524287
    const int b = idx >> 10, j = idx & 1023;
    const float* g = gbuf + (size_t)b * 6144;
    const float pr  = g[j]        + g[3072 + j];
    const float pz  = g[1024 + j] + g[4096 + j];
    const float r = 1.f / (1.f + expf(-pr));
    const float z = 1.f / (1.f + expf(-pz));
    const float n = tanhf(g[2048 + j] + r * g[5120 + j]);
    const float h = (1.f - z) * n + z * h32[idx];
    h32[idx] = h;
    split2h(h, hA0[idx], hA1[idx]);
}

__global__ __launch_bounds__(256) void prep_w16(
    const float* __restrict__ W_ih, const float* __restrict__ W_hh,
    const float* __restrict__ W_out,
    _Float16* __restrict__ Wih0, _Float16* __restrict__ Wih1,
    _Float16* __restrict__ Whh0, _Float16* __restrict__ Whh1,
    _Float16* __restrict__ WoT0, _Float16* __restrict__ WoT1,
    _Float16* __restrict__ W0,   _Float16* __restrict__ W1)
{
    const int idx = blockIdx.x * 256 + threadIdx.x;   // < 3072*1024
    const int n = idx >> 10, k = idx & 1023;
    _Float16 a, b;
    split2h(W_ih[(size_t)n * 1026 + k] * 16.0f, a, b);
    Wih0[idx] = a; Wih1[idx] = b;
    split2h(W_hh[idx] * 16.0f, a, b);
    Whh0[idx] = a; Whh1[idx] = b;
    if (n >= 2048) {                         // gh_n -> interleaved row 4u+3
        const size_t nr = (size_t)(4 * (n - 2048) + 3) * 1024 + k;
        W0[nr] = a; W1[nr] = b;
    }
    if (n < 1024) {                          // W_out rows [4096,5120) + transpose
        split2h(W_out[idx] * 16.0f, a, b);
        W0[(size_t)(4096 + n) * 1024 + k] = a;
        W1[(size_t)(4096 + n) * 1024 + k] = b;
        WoT0[(size_t)k * 1024 + n] = a;
        WoT1[(size_t)k * 1024 + n] = b;
    }
}

__global__ __launch_bounds__(256) void prep_m16(
    const float* __restrict__ enc, const float* __restrict__ h0,
    const float* __restrict__ W_ih,
    const float* __restrict__ b_ih, const float* __restrict__ b_hh,
    const float* __restrict__ b_out,
    _Float16* __restrict__ e0, _Float16* __restrict__ e1,
    _Float16* __restrict__ hA0, _Float16* __restrict__ hA1,
    float* __restrict__ h32, float* __restrict__ bias_big)
{
    const int idx = blockIdx.x * 256 + threadIdx.x;
    if (idx < 524288) {
        split2h(enc[idx], e0[idx], e1[idx]);
        const float hv = h0[idx];
        h32[idx] = hv;
        split2h(hv, hA0[idx], hA1[idx]);
    } else if (idx < 524288 + 5120) {
        const int nn = idx - 524288;
        float v;
        if (nn < 3072) {
            float d = 0.f;
            for (int o = 0; o < 1024; ++o) d += W_ih[(size_t)nn * 1026 + o] * b_out[o];
            v = b_ih[nn] + d + (nn < 2048 ? b_hh[nn] : 0.f);
        } else if (nn < 4096) v = b_hh[nn - 1024];
        else                  v = b_out[nn - 4096];
        bias_big[nn] = v;
    }
}

// ===========================================================================
// fp32 fallback (round-3 verified) for small ws_size.
// ===========================================================================
__global__ __launch_bounds__(256) void gemm_f32(
    const float* __restrict__ A, int lda,
    const float* __restrict__ Bm, int ldb,
    const float* __restrict__ bias,
    const float* __restrict__ act,
    float* __restrict__ dst, int dst_stride, int dst_coloff)
{
    __shared__ float As[16][64];
    __shared__ float Bs[16][64];
    const int t  = threadIdx.x;
    const int tx = t & 15, ty = t >> 4;
    const int row0 = blockIdx.y * 64, col0 = blockIdx.x * 64;
    const int lm = t >> 2;
    const int lk = (t & 3) * 4;
    float acc[4][4] = {};
    for (int kt = 0; kt < 64; ++kt) {
        const int kbase = kt * 16 + lk;
        const float* ap = A + (size_t)(row0 + lm) * lda + kbase;
        const float a0 = ap[0], a1 = ap[1], a2 = ap[2], a3 = ap[3];
        const float* bp = Bm + (size_t)(col0 + lm) * ldb + kbase;
        const float b0 = bp[0], b1 = bp[1], b2 = bp[2], b3 = bp[3];
        __syncthreads();
        As[lk + 0][lm] = a0;   As[lk + 1][lm] = a1;
        As[lk + 2][lm] = a2;   As[lk + 3][lm] = a3;
        Bs[lk + 0][lm] = b0;   Bs[lk + 1][lm] = b1;
        Bs[lk + 2][lm] = b2;   Bs[lk + 3][lm] = b3;
        __syncthreads();
#pragma unroll
        for (int kk = 0; kk < 16; ++kk) {
            const f32x4 a4 = *(const f32x4*)&As[kk][ty * 4];
            const f32x4 b4 = *(const f32x4*)&Bs[kk][tx * 4];
#pragma unroll
            for (int i = 0; i < 4; ++i)
#pragma unroll
                for (int j = 0; j < 4; ++j)
                    acc[i][j] += a4[i] * b4[j];
        }
    }
#pragma unroll
    for (int i = 0; i < 4; ++i) {
        const int row = row0 + ty * 4 + i;
        float a0 = 0.f, a1 = 0.f;
        if (act) { a0 = act[row * 2]; a1 = act[row * 2 + 1]; }
#pragma unroll
        for (int j = 0; j < 4; ++j) {
            const int col = col0 + tx * 4 + j;
            float v = acc[i][j] + (bias ? bias[col] : 0.f);
            if (act) v += a0 * Bm[(size_t)col * ldb + 1024]
                        + a1 * Bm[(size_t)col * ldb + 1025];
            dst[(size_t)row * dst_stride + dst_coloff + col] = v;
        }
    }
}

__global__ __launch_bounds__(256) void ew_gru32(
    const float* __restrict__ gbuf, float* __restrict__ h32)
{
    const int idx = blockIdx.x * 256 + threadIdx.x;
    const int b = idx >> 10, j = idx & 1023;
    const float* g = gbuf + (size_t)b * 6144;
    const float pr  = g[j]        + g[3072 + j];
    const float pz  = g[1024 + j] + g[4096 + j];
    const float r = 1.f / (1.f + expf(-pr));
    const float z = 1.f / (1.f + expf(-pz));
    const float n = tanhf(g[2048 + j] + r * g[5120 + j]);
    h32[idx] = (1.f - z) * n + z * h32[idx];
}

__global__ __launch_bounds__(256) void init_h(const float* __restrict__ h0,
                                              float* __restrict__ h32) {
    const int idx = blockIdx.x * 256 + threadIdx.x;
    h32[idx] = h0[idx];
}

// ---------------------------------------------------------------------------
extern "C" void kernel_launch(void* const* d_in, const int* in_sizes, int n_in,
                              void* d_out, int out_size, void* d_ws, size_t ws_size,
                              hipStream_t stream) {
    const float* enc     = (const float*)d_in[0];
    const float* actions = (const float*)d_in[1];   // [64][512][2]
    const float* h0      = (const float*)d_in[2];
    const float* W_ih    = (const float*)d_in[3];   // [3072][1026]
    const float* W_hh    = (const float*)d_in[4];   // [3072][1024]
    const float* b_ih    = (const float*)d_in[5];
    const float* b_hh    = (const float*)d_in[6];
    const float* W_out   = (const float*)d_in[7];   // [1024][1024]
    const float* b_out   = (const float*)d_in[8];
    float* out = (float*)d_out;                     // [64][512][1024]
    char* ws = (char*)d_ws;

    float* h32  = (float*)ws;                       // 2,097,152 B
    float* gbuf = (float*)(ws + 2097152);           // 12,582,912 -> 14,680,064

    const size_t NEED = 69226496;                   // == r7-proven available
    if (ws_size < NEED) {
        // ---------------- fp32 fallback (round-3 verified) ----------------
        init_h<<<2048, 256, 0, stream>>>(h0, h32);
        const float* e = enc;
        for (int t = 0; t < 64; ++t) {
            gemm_f32<<<dim3(48, 8), 256, 0, stream>>>(
                e, 1024, W_ih, 1026, b_ih, actions + (size_t)t * 1024, gbuf, 6144, 0);
            gemm_f32<<<dim3(48, 8), 256, 0, stream>>>(
                h32, 1024, W_hh, 1024, b_hh, nullptr, gbuf, 6144, 3072);
            ew_gru32<<<2048, 256, 0, stream>>>(gbuf, h32);
            float* ot = out + (size_t)t * 524288;
            gemm_f32<<<dim3(16, 8), 256, 0, stream>>>(
                h32, 1024, W_out, 1024, b_out, nullptr, ot, 1024, 0);
            e = ot;
        }
        return;
    }

    // ---------------- f16 2-plane fused MFMA path ----------------
    size_t off = 14680064;
    auto take = [&](size_t bytes) { char* p = ws + off; off += bytes; return p; };
    _Float16* W0   = (_Float16*)take(10485760);   // interleaved Wbig 5120x1024
    _Float16* W1   = (_Float16*)take(10485760);
    _Float16* Wih0 = (_Float16*)take(6291456);    // 3072x1024 (t0 / wcomb only)
    _Float16* Wih1 = (_Float16*)take(6291456);
    _Float16* Whh0 = (_Float16*)take(6291456);
    _Float16* Whh1 = (_Float16*)take(6291456);
    _Float16* WoT0 = (_Float16*)take(2097152);    // 1024x1024 (wcomb only)
    _Float16* WoT1 = (_Float16*)take(2097152);
    _Float16* e0   = (_Float16*)take(1048576);    // 512x1024
    _Float16* e1   = (_Float16*)take(1048576);
    _Float16* hA0  = (_Float16*)take(1048576);
    _Float16* hA1  = (_Float16*)take(1048576);
    float* bias_big= (float*)take(20480);         // 5120 f32
    // off == 69,226,496
    // h double-buffer B aliased into gbuf (gbuf dead after ew_t0_16):
    _Float16* hB0 = (_Float16*)gbuf;
    _Float16* hB1 = (_Float16*)((char*)gbuf + 1048576);

    prep_w16<<<12288, 256, 0, stream>>>(W_ih, W_hh, W_out,
        Wih0, Wih1, Whh0, Whh1, WoT0, WoT1, W0, W1);
    prep_m16<<<2068, 256, 0, stream>>>(enc, h0, W_ih, b_ih, b_hh, b_out,
        e0, e1, hA0, hA1, h32, bias_big);
    gemm_wcomb16<<<384, 256, 0, stream>>>(Wih0, Wih1, WoT0, WoT1, W_hh, W0, W1);

    // t = 0 (e = enc), then h_1 -> hA.
    gemm_t0_16<<<384, 256, 0, stream>>>(e0, e1, hA0, hA1,
        Wih0, Wih1, Whh0, Whh1, W_ih, b_ih, b_hh, actions, gbuf);
    ew_t0_16<<<2048, 256, 0, stream>>>(gbuf, h32, hA0, hA1);

    // t = 1..63: one fused kernel per step; then final out-only dispatch.
    _Float16 *c0 = hA0, *c1 = hA1, *n0 = hB0, *n1 = hB1;
    for (int t = 1; t < 64; ++t) {
        gemm_step64<<<640, 256, 0, stream>>>(c0, c1, W0, W1, n0, n1, h32,
            out + (size_t)(t - 1) * 524288, bias_big, W_ih,
            actions + (size_t)t * 1024, 0);
        _Float16* s;
        s = c0; c0 = n0; n0 = s;
        s = c1; c1 = n1; n1 = s;
    }
    gemm_step64<<<128, 256, 0, stream>>>(c0, c1, W0, W1, n0, n1, h32,
        out + (size_t)63 * 524288, bias_big, W_ih, actions, 1);
}